// Round 7
// baseline (86.537 us; speedup 1.0000x reference)
//
#include <hip/hip_runtime.h>

#define Bn 4
#define Dd 128
#define Hh 192
#define Ww 192

#define PLANE (Hh * Ww)           // 36864
#define VOL   (Dd * PLANE)
#define N2D   (Bn * PLANE)
#define WARP_OFF ((size_t)N2D)
#define Y_OFF (WARP_OFF + (size_t)Bn * VOL)

// tile geometry: 4 x 8 x 32 voxels per block, 256 threads, 4 voxels/thread
#define DT 4
#define HT 8
#define WT 32
#define NDB (Dd / DT)     // 32
#define NHB (Hh / HT)     // 24
#define NWB (Ww / WT)     // 6
#define NBLK (Bn * NDB * NHB * NWB)   // 18432
#define NCH NDB           // 32 partial chunks per b

// LDS box
#define SZ 14
#define SY 16
#define SXP 44
#define ZSTRIDE (SY * SXP)            // 704
#define LDSF (SZ * ZSTRIDE)           // 9856 floats = 39424 B

typedef float f2 __attribute__((ext_vector_type(2)));
typedef f2 __attribute__((aligned(4))) f2u;
__device__ __forceinline__ f2 load2(const float* p) { return *(const f2u*)p; }

// ---------------- Kernel T: per-block table (matrix + bbox + flags) -------
__global__ __launch_bounds__(256) void tbl_kernel(const float* __restrict__ rot0,
                                                  const float* __restrict__ rot1,
                                                  const float* __restrict__ rot2,
                                                  const float* __restrict__ tr1,
                                                  const float* __restrict__ tr2,
                                                  const float* __restrict__ cp,
                                                  float* __restrict__ tbl) {
    const int id = blockIdx.x * 256 + threadIdx.x;
    if (id >= NBLK) return;
    const int wblk = id % NWB;
    const int t1   = id / NWB;
    const int hblk = t1 % NHB;
    const int t2   = t1 / NHB;
    const int dblk = t2 & (NDB - 1);
    const int b    = t2 >> 5;

    // per-batch matrix
    const float z = rot0[b], y = rot1[b], x = rot2[b];
    const float cz = cosf(z), sz = sinf(z);
    const float cy = cosf(y), sy = sinf(y);
    const float cx = cosf(x), sx = sinf(x);
    const float A0 = cz * cy;
    const float B0 = -sz * cx + cz * sy * sx;
    const float C0 = sz * sx + cz * sy * cx;
    const float A1 = sz * cy;
    const float B1 = cz * cx + sz * sy * sx;
    const float C1 = -cz * sx + sz * sy * cx;
    const float A2 = -sy;
    const float B2 = cy * sx;
    const float C2 = cy * cx;
    const float c0 = cp[b * 3 + 0], c1 = cp[b * 3 + 1], c2 = cp[b * 3 + 2];
    const float E0 = -(A0 * c0 + B0 * c1 + C0 * c2) + c0;
    const float E1 = -(A1 * c0 + B1 * c1 + C1 * c2) + tr1[b] * (float)Hh + c1;
    const float E2 = -(A2 * c0 + B2 * c1 + C2 * c2) + tr2[b] * (float)Ww + c2;

    const int d0 = dblk * DT, h0 = hblk * HT, w0 = wblk * WT;
    const float dlo = (float)d0, dhi = (float)(d0 + DT - 1);
    const float hlo = (float)h0, hhi = (float)(h0 + HT - 1);
    const float wlo = (float)w0, whi = (float)(w0 + WT - 1);

    const float loZ = E0 + fminf(A0 * dlo, A0 * dhi) + fminf(B0 * hlo, B0 * hhi) + fminf(C0 * wlo, C0 * whi);
    const float hiZ = E0 + fmaxf(A0 * dlo, A0 * dhi) + fmaxf(B0 * hlo, B0 * hhi) + fmaxf(C0 * wlo, C0 * whi);
    const float loY = E1 + fminf(A1 * dlo, A1 * dhi) + fminf(B1 * hlo, B1 * hhi) + fminf(C1 * wlo, C1 * whi);
    const float hiY = E1 + fmaxf(A1 * dlo, A1 * dhi) + fmaxf(B1 * hlo, B1 * hhi) + fmaxf(C1 * wlo, C1 * whi);
    const float loX = E2 + fminf(A2 * dlo, A2 * dhi) + fminf(B2 * hlo, B2 * hhi) + fminf(C2 * wlo, C2 * whi);
    const float hiX = E2 + fmaxf(A2 * dlo, A2 * dhi) + fmaxf(B2 * hlo, B2 * hhi) + fmaxf(C2 * wlo, C2 * whi);

    const int lz = max(0, (int)floorf(loZ) - 1);
    const int hz = min(Dd - 1, (int)floorf(hiZ) + 2);
    const int ly = max(0, (int)floorf(loY) - 1);
    const int hy = min(Hh - 1, (int)floorf(hiY) + 2);
    const int lx = max(0, (int)floorf(loX) - 1);
    const int lx4 = lx & ~3;
    const int hx = min(Ww - 2, (int)floorf(hiX) + 2);

    const bool fits = (hz - lz <= SZ - 1) && (hy - ly <= SY - 1) && (hx - lx4 <= SXP - 2);
    const bool interior = (loZ >= 0.01f) && (hiZ < (float)(Dd - 1) - 0.01f) &&
                          (loY >= 0.01f) && (hiY < (float)(Hh - 1) - 0.01f) &&
                          (loX >= 0.01f) && (hiX < (float)(Ww - 1) - 0.01f);

    // box-relative bases at (d0, h0, w0)
    const float bz = E0 + A0 * dlo + B0 * hlo + C0 * wlo - (float)lz;
    const float by = E1 + A1 * dlo + B1 * hlo + C1 * wlo - (float)ly;
    const float bx = E2 + A2 * dlo + B2 * hlo + C2 * wlo - (float)lx4;

    float* T = tbl + (size_t)id * 16;
    T[0] = A0; T[1] = B0; T[2]  = C0; T[3]  = bz;
    T[4] = A1; T[5] = B1; T[6]  = C1; T[7]  = by;
    T[8] = A2; T[9] = B2; T[10] = C2; T[11] = bx;
    int* TI = (int*)T;
    TI[12] = lz; TI[13] = ly; TI[14] = lx4;
    TI[15] = (fits ? 1 : 0) | (interior ? 2 : 0) |
             (b << 2) | (dblk << 4) | (hblk << 9) | (wblk << 14);
}

// ---------------- Kernel B: LDS-tiled warp ----------------
template <bool WP>
__global__ __launch_bounds__(256) void warp_tiled(const float* __restrict__ x,
                                                  const float* __restrict__ tbl,
                                                  float* __restrict__ out,
                                                  float* __restrict__ partial) {
    __shared__ __align__(16) float box[LDSF];

    // XCD-aware swizzle
    const int g  = blockIdx.x;
    const int wl = (g & 7) * (NBLK / 8) + (g >> 3);

    const float4* T4 = (const float4*)(tbl + (size_t)wl * 16);
    const float4 r0 = T4[0], r1 = T4[1], r2 = T4[2];
    const int4   r3 = ((const int4*)T4)[3];
    const int lz = r3.x, ly = r3.y, lx4 = r3.z, fl = r3.w;
    const bool fits = fl & 1, interior = fl & 2;
    const int b    = (fl >> 2) & 3;
    const int dblk = (fl >> 4) & 31;
    const int hblk = (fl >> 9) & 31;
    const int wblk = (fl >> 14) & 7;
    const int d0 = dblk * DT, h0 = hblk * HT, w0 = wblk * WT;

    const float A0 = r0.x, B0 = r0.y, C0 = r0.z, bz = r0.w;
    const float A1 = r1.x, B1 = r1.y, C1 = r1.z, by = r1.w;
    const float A2 = r2.x, B2 = r2.y, C2 = r2.z, bx = r2.w;

    const int t = threadIdx.x;
    const int w_in = t & 31;
    const int h_in = t >> 5;           // 0..7

    const float fh = (float)h_in, fw = (float)w_in;
    // box-relative per-thread bases at j=0
    const float fz0 = bz + B0 * fh + C0 * fw;
    const float fy0 = by + B1 * fh + C1 * fw;
    const float fx0 = bx + B2 * fh + C2 * fw;

    const float* __restrict__ V = x + (size_t)b * VOL;
    float* __restrict__ obase = out + WARP_OFF + (size_t)b * VOL +
                                (size_t)d0 * PLANE + (size_t)(h0 + h_in) * Ww + (w0 + w_in);

    float sum = 0.0f;

    if (fits) {
        // ---- staging: box[z][yy][x], pow2-decoded two-pass ----
        const int mz  = Dd - 1 - lz;          // max valid rel z
        const int my  = Hh - 1 - ly;
        const int mx4 = (Ww - 4) - lx4;       // max valid rel x (4-aligned col start)
        // pass A: qc = 0..7
        {
            const int qc  = t & 7;
            const int yy  = (t >> 3) & 15;
            const int zp  = t >> 7;           // 0/1
            const float* Vb = V + (size_t)lz * PLANE + (ly + min(yy, my)) * Ww + lx4 + min(4 * qc, mx4);
            float* Lb = box + yy * SXP + 4 * qc;
            #pragma unroll
            for (int i = 0; i < 7; ++i) {
                const int zrel = i * 2 + zp;                   // 0..13
                const float4 v = *(const float4*)(Vb + (size_t)min(zrel, mz) * PLANE);
                *(float4*)(Lb + zrel * ZSTRIDE) = v;
            }
        }
        // pass B: qc = 8..10
        {
            const int q2 = t & 3;
            const int yy = (t >> 2) & 15;
            const int zp = t >> 6;            // 0..3
            if (q2 < 3) {
                const int qc = 8 + q2;
                const float* Vb = V + (size_t)lz * PLANE + (ly + min(yy, my)) * Ww + lx4 + min(4 * qc, mx4);
                float* Lb = box + yy * SXP + 4 * qc;
                #pragma unroll
                for (int i = 0; i < 4; ++i) {
                    const int zrel = i * 4 + zp;               // 0..15
                    if (zrel < SZ) {
                        const float4 v = *(const float4*)(Vb + (size_t)min(zrel, mz) * PLANE);
                        *(float4*)(Lb + zrel * ZSTRIDE) = v;
                    }
                }
            }
        }
        __syncthreads();

        if (interior) {
            #pragma unroll
            for (int j = 0; j < 4; ++j) {
                const float fd = (float)j;
                const float gz = fmaf(A0, fd, fz0);
                const float gy = fmaf(A1, fd, fy0);
                const float gx = fmaf(A2, fd, fx0);
                const float fz = floorf(gz), fy = floorf(gy), fx = floorf(gx);
                const float tz = gz - fz, ty = gy - fy, tx = gx - fx;
                const int izr = (int)fz, iyr = (int)fy, ixr = (int)fx;
                const int base = izr * ZSTRIDE + iyr * SXP + ixr;

                const float q00l = box[base],                  q00h = box[base + 1];
                const float q01l = box[base + SXP],            q01h = box[base + SXP + 1];
                const float q10l = box[base + ZSTRIDE],        q10h = box[base + ZSTRIDE + 1];
                const float q11l = box[base + ZSTRIDE + SXP],  q11h = box[base + ZSTRIDE + SXP + 1];

                const float wx0 = 1.0f - tx, wy0 = 1.0f - ty, wz0 = 1.0f - tz;
                const float v00 = fmaf(wx0, q00l, tx * q00h);
                const float v01 = fmaf(wx0, q01l, tx * q01h);
                const float v10 = fmaf(wx0, q10l, tx * q10h);
                const float v11 = fmaf(wx0, q11l, tx * q11h);
                const float vz0 = fmaf(wy0, v00, ty * v01);
                const float vz1 = fmaf(wy0, v10, ty * v11);
                const float val = fmaf(wz0, vz0, tz * vz1);

                __builtin_nontemporal_store(val, obase + (size_t)j * PLANE);
                sum += val;
            }
        } else {
            // masked LDS path (boundary tiles); absolute coords
            const float fz0a = fz0 + (float)lz;
            const float fy0a = fy0 + (float)ly;
            const float fx0a = fx0 + (float)lx4;
            #pragma unroll
            for (int j = 0; j < 4; ++j) {
                const float fd = (float)j;
                const float gz = fmaf(A0, fd, fz0a);
                const float gy = fmaf(A1, fd, fy0a);
                const float gx = fmaf(A2, fd, fx0a);

                const float fz = floorf(gz), fy = floorf(gy), fx = floorf(gx);
                const float tz = gz - fz, ty = gy - fy, tx = gx - fx;
                const int iz = (int)fz, iy = (int)fy, ix = (int)fx;

                const float wz0 = ((unsigned)iz       < (unsigned)Dd) ? (1.0f - tz) : 0.0f;
                const float wz1 = ((unsigned)(iz + 1) < (unsigned)Dd) ? tz : 0.0f;
                const float wy0 = ((unsigned)iy       < (unsigned)Hh) ? (1.0f - ty) : 0.0f;
                const float wy1 = ((unsigned)(iy + 1) < (unsigned)Hh) ? ty : 0.0f;
                const float wx0 = ((unsigned)ix       < (unsigned)Ww) ? (1.0f - tx) : 0.0f;
                const float wx1 = ((unsigned)(ix + 1) < (unsigned)Ww) ? tx : 0.0f;

                const bool right  = (ix >= Ww - 1);
                const bool leftok = (ix >= 0);
                const float WL = (right ? 0.0f : wx0) + (leftok ? 0.0f : wx1);
                const float WH = (right ? wx0 : 0.0f) + (leftok ? wx1 : 0.0f);

                const int zc0 = min(max(iz, 0), Dd - 1) - lz;
                const int zc1 = min(max(iz + 1, 0), Dd - 1) - lz;
                const int yc0 = min(max(iy, 0), Hh - 1) - ly;
                const int yc1 = min(max(iy + 1, 0), Hh - 1) - ly;
                const int ixl = min(max(ix, 0), Ww - 2);
                const int col = max(ixl - lx4, 0);

                const int b00 = zc0 * ZSTRIDE + yc0 * SXP + col;
                const int b01 = zc0 * ZSTRIDE + yc1 * SXP + col;
                const int b10 = zc1 * ZSTRIDE + yc0 * SXP + col;
                const int b11 = zc1 * ZSTRIDE + yc1 * SXP + col;

                const float v00 = fmaf(WL, box[b00], WH * box[b00 + 1]);
                const float v01 = fmaf(WL, box[b01], WH * box[b01 + 1]);
                const float v10 = fmaf(WL, box[b10], WH * box[b10 + 1]);
                const float v11 = fmaf(WL, box[b11], WH * box[b11 + 1]);

                const float vz0 = fmaf(wy0, v00, wy1 * v01);
                const float vz1 = fmaf(wy0, v10, wy1 * v11);
                const float val = fmaf(wz0, vz0, wz1 * vz1);

                __builtin_nontemporal_store(val, obase + (size_t)j * PLANE);
                sum += val;
            }
        }
    } else {
        // global-gather fallback
        const float fz0a = fz0 + (float)lz;
        const float fy0a = fy0 + (float)ly;
        const float fx0a = fx0 + (float)lx4;
        #pragma unroll
        for (int j = 0; j < 4; ++j) {
            const float fd = (float)j;
            const float gz = fmaf(A0, fd, fz0a);
            const float gy = fmaf(A1, fd, fy0a);
            const float gx = fmaf(A2, fd, fx0a);

            const float fz = floorf(gz), fy = floorf(gy), fx = floorf(gx);
            const float tz = gz - fz, ty = gy - fy, tx = gx - fx;
            const int iz = (int)fz, iy = (int)fy, ix = (int)fx;

            const float wz0 = ((unsigned)iz       < (unsigned)Dd) ? (1.0f - tz) : 0.0f;
            const float wz1 = ((unsigned)(iz + 1) < (unsigned)Dd) ? tz : 0.0f;
            const float wy0 = ((unsigned)iy       < (unsigned)Hh) ? (1.0f - ty) : 0.0f;
            const float wy1 = ((unsigned)(iy + 1) < (unsigned)Hh) ? ty : 0.0f;
            const float wx0 = ((unsigned)ix       < (unsigned)Ww) ? (1.0f - tx) : 0.0f;
            const float wx1 = ((unsigned)(ix + 1) < (unsigned)Ww) ? tx : 0.0f;

            const bool right  = (ix >= Ww - 1);
            const bool leftok = (ix >= 0);
            const float WL = (right ? 0.0f : wx0) + (leftok ? 0.0f : wx1);
            const float WH = (right ? wx0 : 0.0f) + (leftok ? wx1 : 0.0f);

            const int iz0c = min(max(iz, 0), Dd - 1);
            const int iz1c = min(max(iz + 1, 0), Dd - 1);
            const int iy0c = min(max(iy, 0), Hh - 1);
            const int iy1c = min(max(iy + 1, 0), Hh - 1);
            const int ixl  = min(max(ix, 0), Ww - 2);

            const f2 q00 = load2(V + (size_t)iz0c * PLANE + iy0c * Ww + ixl);
            const f2 q01 = load2(V + (size_t)iz0c * PLANE + iy1c * Ww + ixl);
            const f2 q10 = load2(V + (size_t)iz1c * PLANE + iy0c * Ww + ixl);
            const f2 q11 = load2(V + (size_t)iz1c * PLANE + iy1c * Ww + ixl);

            const float v00 = fmaf(WL, q00.x, WH * q00.y);
            const float v01 = fmaf(WL, q01.x, WH * q01.y);
            const float v10 = fmaf(WL, q10.x, WH * q10.y);
            const float v11 = fmaf(WL, q11.x, WH * q11.y);

            const float vz0 = fmaf(wy0, v00, wy1 * v01);
            const float vz1 = fmaf(wy0, v10, wy1 * v11);
            const float val = fmaf(wz0, vz0, wz1 * vz1);

            __builtin_nontemporal_store(val, obase + (size_t)j * PLANE);
            sum += val;
        }
    }

    if (WP) {
        partial[((size_t)(b * NCH + dblk) * Hh + (h0 + h_in)) * Ww + (w0 + w_in)] = sum;
    }
}

// ---------------- Kernel C: reduce partials -> x_2d, copy y -------------
__global__ __launch_bounds__(256) void reduce_kernel(const float* __restrict__ partial,
                                                     const float* __restrict__ yin,
                                                     float* __restrict__ out) {
    const int idx = blockIdx.x * 256 + threadIdx.x;
    if (idx >= N2D) return;
    const int b = idx / PLANE;
    const int rem = idx - b * PLANE;
    const float* p = partial + (size_t)b * NCH * PLANE + rem;
    float s = 0.0f;
    #pragma unroll
    for (int c = 0; c < NCH; ++c) s += p[(size_t)c * PLANE];
    out[idx] = s * (1.0f / (float)Dd);
    out[Y_OFF + idx] = yin[idx];
}

// ---------------- Fallback reduce: read x_warp directly -----------------
__global__ __launch_bounds__(256) void reduce_fallback_kernel(const float* __restrict__ yin,
                                                              float* __restrict__ out) {
    const int idx = blockIdx.x * 256 + threadIdx.x;
    if (idx >= N2D) return;
    const int b = idx / PLANE;
    const int rem = idx - b * PLANE;
    const float* p = out + WARP_OFF + (size_t)b * VOL + rem;
    float s = 0.0f;
    #pragma unroll 8
    for (int d = 0; d < Dd; ++d) s += p[(size_t)d * PLANE];
    out[idx] = s * (1.0f / (float)Dd);
    out[Y_OFF + idx] = yin[idx];
}

extern "C" void kernel_launch(void* const* d_in, const int* in_sizes, int n_in,
                              void* d_out, int out_size, void* d_ws, size_t ws_size,
                              hipStream_t stream) {
    const float* x    = (const float*)d_in[0];
    const float* yin  = (const float*)d_in[1];
    const float* rot0 = (const float*)d_in[2];
    const float* rot1 = (const float*)d_in[3];
    const float* rot2 = (const float*)d_in[4];
    const float* tr1  = (const float*)d_in[5];
    const float* tr2  = (const float*)d_in[6];
    const float* cp   = (const float*)d_in[7];

    float* tbl = (float*)d_ws;                       // NBLK*16 floats = 1.18 MB
    float* partial = tbl + (size_t)NBLK * 16;        // Bn*NCH*PLANE floats = 18.9 MB
    const size_t need = ((size_t)NBLK * 16 + (size_t)Bn * NCH * PLANE) * sizeof(float);

    tbl_kernel<<<(NBLK + 255) / 256, 256, 0, stream>>>(rot0, rot1, rot2, tr1, tr2, cp, tbl);

    if (ws_size >= need) {
        warp_tiled<true><<<NBLK, 256, 0, stream>>>(x, tbl, (float*)d_out, partial);
        reduce_kernel<<<(N2D + 255) / 256, 256, 0, stream>>>(partial, yin, (float*)d_out);
    } else {
        warp_tiled<false><<<NBLK, 256, 0, stream>>>(x, tbl, (float*)d_out, partial);
        reduce_fallback_kernel<<<(N2D + 255) / 256, 256, 0, stream>>>(yin, (float*)d_out);
    }
}

// Round 8
// 63.442 us; speedup vs baseline: 1.3640x; 1.3640x over previous
//
#include <hip/hip_runtime.h>

#define Bn 4
#define Dd 128
#define Hh 192
#define Ww 192

#define PLANE (Hh * Ww)           // 36864
#define VOL   (Dd * PLANE)
#define N2D   (Bn * PLANE)
#define WARP_OFF ((size_t)N2D)
#define Y_OFF (WARP_OFF + (size_t)Bn * VOL)

// tile geometry: 4 x 8 x 32 voxels per block, 256 threads, 4 voxels/thread
#define DT 4
#define HT 8
#define WT 32
#define NDB (Dd / DT)     // 32
#define NHB (Hh / HT)     // 24
#define NWB (Ww / WT)     // 6
#define NBLK (Bn * NDB * NHB * NWB)   // 18432
#define NCH NDB           // 32 partial chunks per b

// LDS box: [SZ][SY][SXP]; one z-slice = 768 floats = 3 chunks of 256 floats
// (exactly 3 global_load_lds dwordx4 instructions, 64 lanes x 16B each)
#define SZ 13
#define SY 16
#define SXP 48
#define ZSTRIDE (SY * SXP)            // 768
#define LDSF (SZ * ZSTRIDE)           // 9984 floats = 39936 B

typedef float f2 __attribute__((ext_vector_type(2)));
typedef f2 __attribute__((aligned(4))) f2u;
__device__ __forceinline__ f2 load2(const float* p) { return *(const f2u*)p; }

__device__ __forceinline__ void gload_lds16(const float* g, float* l) {
    __builtin_amdgcn_global_load_lds(
        (const __attribute__((address_space(1))) void*)g,
        (__attribute__((address_space(3))) void*)l,
        16, 0, 0);
}

// ---------------- Kernel T: per-block table (matrix + bbox + flags) -------
__global__ __launch_bounds__(256) void tbl_kernel(const float* __restrict__ rot0,
                                                  const float* __restrict__ rot1,
                                                  const float* __restrict__ rot2,
                                                  const float* __restrict__ tr1,
                                                  const float* __restrict__ tr2,
                                                  const float* __restrict__ cp,
                                                  float* __restrict__ tbl) {
    const int id = blockIdx.x * 256 + threadIdx.x;
    if (id >= NBLK) return;
    const int wblk = id % NWB;
    const int t1   = id / NWB;
    const int hblk = t1 % NHB;
    const int t2   = t1 / NHB;
    const int dblk = t2 & (NDB - 1);
    const int b    = t2 >> 5;

    const float z = rot0[b], y = rot1[b], x = rot2[b];
    const float cz = cosf(z), sz = sinf(z);
    const float cy = cosf(y), sy = sinf(y);
    const float cx = cosf(x), sx = sinf(x);
    const float A0 = cz * cy;
    const float B0 = -sz * cx + cz * sy * sx;
    const float C0 = sz * sx + cz * sy * cx;
    const float A1 = sz * cy;
    const float B1 = cz * cx + sz * sy * sx;
    const float C1 = -cz * sx + sz * sy * cx;
    const float A2 = -sy;
    const float B2 = cy * sx;
    const float C2 = cy * cx;
    const float c0 = cp[b * 3 + 0], c1 = cp[b * 3 + 1], c2 = cp[b * 3 + 2];
    const float E0 = -(A0 * c0 + B0 * c1 + C0 * c2) + c0;
    const float E1 = -(A1 * c0 + B1 * c1 + C1 * c2) + tr1[b] * (float)Hh + c1;
    const float E2 = -(A2 * c0 + B2 * c1 + C2 * c2) + tr2[b] * (float)Ww + c2;

    const int d0 = dblk * DT, h0 = hblk * HT, w0 = wblk * WT;
    const float dlo = (float)d0, dhi = (float)(d0 + DT - 1);
    const float hlo = (float)h0, hhi = (float)(h0 + HT - 1);
    const float wlo = (float)w0, whi = (float)(w0 + WT - 1);

    const float loZ = E0 + fminf(A0 * dlo, A0 * dhi) + fminf(B0 * hlo, B0 * hhi) + fminf(C0 * wlo, C0 * whi);
    const float hiZ = E0 + fmaxf(A0 * dlo, A0 * dhi) + fmaxf(B0 * hlo, B0 * hhi) + fmaxf(C0 * wlo, C0 * whi);
    const float loY = E1 + fminf(A1 * dlo, A1 * dhi) + fminf(B1 * hlo, B1 * hhi) + fminf(C1 * wlo, C1 * whi);
    const float hiY = E1 + fmaxf(A1 * dlo, A1 * dhi) + fmaxf(B1 * hlo, B1 * hhi) + fmaxf(C1 * wlo, C1 * whi);
    const float loX = E2 + fminf(A2 * dlo, A2 * dhi) + fminf(B2 * hlo, B2 * hhi) + fminf(C2 * wlo, C2 * whi);
    const float hiX = E2 + fmaxf(A2 * dlo, A2 * dhi) + fmaxf(B2 * hlo, B2 * hhi) + fmaxf(C2 * wlo, C2 * whi);

    const int lz = max(0, (int)floorf(loZ) - 1);
    const int hz = min(Dd - 1, (int)floorf(hiZ) + 2);
    const int ly = max(0, (int)floorf(loY) - 1);
    const int hy = min(Hh - 1, (int)floorf(hiY) + 2);
    const int lx = max(0, (int)floorf(loX) - 1);
    const int lx4 = lx & ~3;
    const int hx = min(Ww - 2, (int)floorf(hiX) + 2);

    const bool fits = (hz - lz <= SZ - 1) && (hy - ly <= SY - 1) && (hx - lx4 <= SXP - 2);
    const bool interior = (loZ >= 0.01f) && (hiZ < (float)(Dd - 1) - 0.01f) &&
                          (loY >= 0.01f) && (hiY < (float)(Hh - 1) - 0.01f) &&
                          (loX >= 0.01f) && (hiX < (float)(Ww - 1) - 0.01f);

    const float bz = E0 + A0 * dlo + B0 * hlo + C0 * wlo - (float)lz;
    const float by = E1 + A1 * dlo + B1 * hlo + C1 * wlo - (float)ly;
    const float bx = E2 + A2 * dlo + B2 * hlo + C2 * wlo - (float)lx4;

    float* T = tbl + (size_t)id * 16;
    T[0] = A0; T[1] = B0; T[2]  = C0; T[3]  = bz;
    T[4] = A1; T[5] = B1; T[6]  = C1; T[7]  = by;
    T[8] = A2; T[9] = B2; T[10] = C2; T[11] = bx;
    int* TI = (int*)T;
    TI[12] = lz; TI[13] = ly; TI[14] = lx4;
    TI[15] = (fits ? 1 : 0) | (interior ? 2 : 0) |
             (b << 2) | (dblk << 4) | (hblk << 9) | (wblk << 14);
}

// ---------------- Kernel B: LDS-tiled warp (DMA staging) ----------------
template <bool WP>
__global__ __launch_bounds__(256) void warp_tiled(const float* __restrict__ x,
                                                  const float* __restrict__ tbl,
                                                  float* __restrict__ out,
                                                  float* __restrict__ partial) {
    __shared__ __align__(16) float box[LDSF];

    // XCD-aware swizzle
    const int g  = blockIdx.x;
    const int wl = (g & 7) * (NBLK / 8) + (g >> 3);

    const float4* T4 = (const float4*)(tbl + (size_t)wl * 16);
    const float4 r0 = T4[0], r1 = T4[1], r2 = T4[2];
    const int4   r3 = ((const int4*)T4)[3];
    const int lz = r3.x, ly = r3.y, lx4 = r3.z, fl = r3.w;
    const bool fits = fl & 1, interior = fl & 2;
    const int b    = (fl >> 2) & 3;
    const int dblk = (fl >> 4) & 31;
    const int hblk = (fl >> 9) & 31;
    const int wblk = (fl >> 14) & 7;
    const int d0 = dblk * DT, h0 = hblk * HT, w0 = wblk * WT;

    const float A0 = r0.x, B0 = r0.y, C0 = r0.z, bz = r0.w;
    const float A1 = r1.x, B1 = r1.y, C1 = r1.z, by = r1.w;
    const float A2 = r2.x, B2 = r2.y, C2 = r2.z, bx = r2.w;

    const int t = threadIdx.x;
    const int w_in = t & 31;
    const int h_in = t >> 5;           // 0..7

    const float fh = (float)h_in, fw = (float)w_in;
    const float fz0 = bz + B0 * fh + C0 * fw;
    const float fy0 = by + B1 * fh + C1 * fw;
    const float fx0 = bx + B2 * fh + C2 * fw;

    const float* __restrict__ V = x + (size_t)b * VOL;
    float* __restrict__ obase = out + WARP_OFF + (size_t)b * VOL +
                                (size_t)d0 * PLANE + (size_t)(h0 + h_in) * Ww + (w0 + w_in);

    float sum = 0.0f;

    if (fits) {
        // ---- staging via global_load_lds: per z-slice, 3 chunks of 64x16B ----
        const int wid  = t >> 6;       // 0..3
        const int lane = t & 63;
        // per-lane (row,col) for each chunk c: idx = c*64 + lane; row=idx/12, col=(idx%12)*4
        const int i0 = lane,       r0i = i0 / 12, c0i = (i0 - r0i * 12) * 4;
        const int i1 = 64 + lane,  r1i = i1 / 12, c1i = (i1 - r1i * 12) * 4;
        const int i2 = 128 + lane, r2i = i2 / 12, c2i = (i2 - r2i * 12) * 4;
        const int off0 = min(ly + r0i, Hh - 1) * Ww + min(lx4 + c0i, Ww - 4);
        const int off1 = min(ly + r1i, Hh - 1) * Ww + min(lx4 + c1i, Ww - 4);
        const int off2 = min(ly + r2i, Hh - 1) * Ww + min(lx4 + c2i, Ww - 4);

        for (int z = wid; z < SZ; z += 4) {
            const float* Vz = V + (size_t)min(lz + z, Dd - 1) * PLANE;
            float* Lz = box + z * ZSTRIDE;
            gload_lds16(Vz + off0, Lz);
            gload_lds16(Vz + off1, Lz + 256);
            gload_lds16(Vz + off2, Lz + 512);
        }
        __syncthreads();

        if (interior) {
            #pragma unroll
            for (int j = 0; j < 4; ++j) {
                const float fd = (float)j;
                const float gz = fmaf(A0, fd, fz0);
                const float gy = fmaf(A1, fd, fy0);
                const float gx = fmaf(A2, fd, fx0);
                const float fz = floorf(gz), fy = floorf(gy), fx = floorf(gx);
                const float tz = gz - fz, ty = gy - fy, tx = gx - fx;
                const int izr = (int)fz, iyr = (int)fy, ixr = (int)fx;
                const int base = izr * ZSTRIDE + iyr * SXP + ixr;

                const f2 qa = load2(&box[base]);
                const f2 qb = load2(&box[base + SXP]);
                const f2 qc = load2(&box[base + ZSTRIDE]);
                const f2 qd = load2(&box[base + ZSTRIDE + SXP]);

                const float wx0 = 1.0f - tx, wy0 = 1.0f - ty, wz0 = 1.0f - tz;
                const float v00 = fmaf(wx0, qa.x, tx * qa.y);
                const float v01 = fmaf(wx0, qb.x, tx * qb.y);
                const float v10 = fmaf(wx0, qc.x, tx * qc.y);
                const float v11 = fmaf(wx0, qd.x, tx * qd.y);
                const float vz0 = fmaf(wy0, v00, ty * v01);
                const float vz1 = fmaf(wy0, v10, ty * v11);
                const float val = fmaf(wz0, vz0, tz * vz1);

                __builtin_nontemporal_store(val, obase + (size_t)j * PLANE);
                sum += val;
            }
        } else {
            const float fz0a = fz0 + (float)lz;
            const float fy0a = fy0 + (float)ly;
            const float fx0a = fx0 + (float)lx4;
            #pragma unroll
            for (int j = 0; j < 4; ++j) {
                const float fd = (float)j;
                const float gz = fmaf(A0, fd, fz0a);
                const float gy = fmaf(A1, fd, fy0a);
                const float gx = fmaf(A2, fd, fx0a);

                const float fz = floorf(gz), fy = floorf(gy), fx = floorf(gx);
                const float tz = gz - fz, ty = gy - fy, tx = gx - fx;
                const int iz = (int)fz, iy = (int)fy, ix = (int)fx;

                const float wz0 = ((unsigned)iz       < (unsigned)Dd) ? (1.0f - tz) : 0.0f;
                const float wz1 = ((unsigned)(iz + 1) < (unsigned)Dd) ? tz : 0.0f;
                const float wy0 = ((unsigned)iy       < (unsigned)Hh) ? (1.0f - ty) : 0.0f;
                const float wy1 = ((unsigned)(iy + 1) < (unsigned)Hh) ? ty : 0.0f;
                const float wx0 = ((unsigned)ix       < (unsigned)Ww) ? (1.0f - tx) : 0.0f;
                const float wx1 = ((unsigned)(ix + 1) < (unsigned)Ww) ? tx : 0.0f;

                const bool right  = (ix >= Ww - 1);
                const bool leftok = (ix >= 0);
                const float WL = (right ? 0.0f : wx0) + (leftok ? 0.0f : wx1);
                const float WH = (right ? wx0 : 0.0f) + (leftok ? wx1 : 0.0f);

                const int zc0 = min(max(iz, 0), Dd - 1) - lz;
                const int zc1 = min(max(iz + 1, 0), Dd - 1) - lz;
                const int yc0 = min(max(iy, 0), Hh - 1) - ly;
                const int yc1 = min(max(iy + 1, 0), Hh - 1) - ly;
                const int ixl = min(max(ix, 0), Ww - 2);
                const int col = max(ixl - lx4, 0);

                const int b00 = zc0 * ZSTRIDE + yc0 * SXP + col;
                const int b01 = zc0 * ZSTRIDE + yc1 * SXP + col;
                const int b10 = zc1 * ZSTRIDE + yc0 * SXP + col;
                const int b11 = zc1 * ZSTRIDE + yc1 * SXP + col;

                const f2 qa = load2(&box[b00]);
                const f2 qb = load2(&box[b01]);
                const f2 qc = load2(&box[b10]);
                const f2 qd = load2(&box[b11]);

                const float v00 = fmaf(WL, qa.x, WH * qa.y);
                const float v01 = fmaf(WL, qb.x, WH * qb.y);
                const float v10 = fmaf(WL, qc.x, WH * qc.y);
                const float v11 = fmaf(WL, qd.x, WH * qd.y);

                const float vz0 = fmaf(wy0, v00, wy1 * v01);
                const float vz1 = fmaf(wy0, v10, wy1 * v11);
                const float val = fmaf(wz0, vz0, wz1 * vz1);

                __builtin_nontemporal_store(val, obase + (size_t)j * PLANE);
                sum += val;
            }
        }
    } else {
        // global-gather fallback
        const float fz0a = fz0 + (float)lz;
        const float fy0a = fy0 + (float)ly;
        const float fx0a = fx0 + (float)lx4;
        #pragma unroll
        for (int j = 0; j < 4; ++j) {
            const float fd = (float)j;
            const float gz = fmaf(A0, fd, fz0a);
            const float gy = fmaf(A1, fd, fy0a);
            const float gx = fmaf(A2, fd, fx0a);

            const float fz = floorf(gz), fy = floorf(gy), fx = floorf(gx);
            const float tz = gz - fz, ty = gy - fy, tx = gx - fx;
            const int iz = (int)fz, iy = (int)fy, ix = (int)fx;

            const float wz0 = ((unsigned)iz       < (unsigned)Dd) ? (1.0f - tz) : 0.0f;
            const float wz1 = ((unsigned)(iz + 1) < (unsigned)Dd) ? tz : 0.0f;
            const float wy0 = ((unsigned)iy       < (unsigned)Hh) ? (1.0f - ty) : 0.0f;
            const float wy1 = ((unsigned)(iy + 1) < (unsigned)Hh) ? ty : 0.0f;
            const float wx0 = ((unsigned)ix       < (unsigned)Ww) ? (1.0f - tx) : 0.0f;
            const float wx1 = ((unsigned)(ix + 1) < (unsigned)Ww) ? tx : 0.0f;

            const bool right  = (ix >= Ww - 1);
            const bool leftok = (ix >= 0);
            const float WL = (right ? 0.0f : wx0) + (leftok ? 0.0f : wx1);
            const float WH = (right ? wx0 : 0.0f) + (leftok ? wx1 : 0.0f);

            const int iz0c = min(max(iz, 0), Dd - 1);
            const int iz1c = min(max(iz + 1, 0), Dd - 1);
            const int iy0c = min(max(iy, 0), Hh - 1);
            const int iy1c = min(max(iy + 1, 0), Hh - 1);
            const int ixl  = min(max(ix, 0), Ww - 2);

            const f2 q00 = load2(V + (size_t)iz0c * PLANE + iy0c * Ww + ixl);
            const f2 q01 = load2(V + (size_t)iz0c * PLANE + iy1c * Ww + ixl);
            const f2 q10 = load2(V + (size_t)iz1c * PLANE + iy0c * Ww + ixl);
            const f2 q11 = load2(V + (size_t)iz1c * PLANE + iy1c * Ww + ixl);

            const float v00 = fmaf(WL, q00.x, WH * q00.y);
            const float v01 = fmaf(WL, q01.x, WH * q01.y);
            const float v10 = fmaf(WL, q10.x, WH * q10.y);
            const float v11 = fmaf(WL, q11.x, WH * q11.y);

            const float vz0 = fmaf(wy0, v00, wy1 * v01);
            const float vz1 = fmaf(wy0, v10, wy1 * v11);
            const float val = fmaf(wz0, vz0, wz1 * vz1);

            __builtin_nontemporal_store(val, obase + (size_t)j * PLANE);
            sum += val;
        }
    }

    if (WP) {
        partial[((size_t)(b * NCH + dblk) * Hh + (h0 + h_in)) * Ww + (w0 + w_in)] = sum;
    }
}

// ---------------- Kernel C: reduce partials -> x_2d, copy y -------------
__global__ __launch_bounds__(256) void reduce_kernel(const float* __restrict__ partial,
                                                     const float* __restrict__ yin,
                                                     float* __restrict__ out) {
    const int idx = blockIdx.x * 256 + threadIdx.x;
    if (idx >= N2D) return;
    const int b = idx / PLANE;
    const int rem = idx - b * PLANE;
    const float* p = partial + (size_t)b * NCH * PLANE + rem;
    float s = 0.0f;
    #pragma unroll
    for (int c = 0; c < NCH; ++c) s += p[(size_t)c * PLANE];
    out[idx] = s * (1.0f / (float)Dd);
    out[Y_OFF + idx] = yin[idx];
}

// ---------------- Fallback reduce: read x_warp directly -----------------
__global__ __launch_bounds__(256) void reduce_fallback_kernel(const float* __restrict__ yin,
                                                              float* __restrict__ out) {
    const int idx = blockIdx.x * 256 + threadIdx.x;
    if (idx >= N2D) return;
    const int b = idx / PLANE;
    const int rem = idx - b * PLANE;
    const float* p = out + WARP_OFF + (size_t)b * VOL + rem;
    float s = 0.0f;
    #pragma unroll 8
    for (int d = 0; d < Dd; ++d) s += p[(size_t)d * PLANE];
    out[idx] = s * (1.0f / (float)Dd);
    out[Y_OFF + idx] = yin[idx];
}

extern "C" void kernel_launch(void* const* d_in, const int* in_sizes, int n_in,
                              void* d_out, int out_size, void* d_ws, size_t ws_size,
                              hipStream_t stream) {
    const float* x    = (const float*)d_in[0];
    const float* yin  = (const float*)d_in[1];
    const float* rot0 = (const float*)d_in[2];
    const float* rot1 = (const float*)d_in[3];
    const float* rot2 = (const float*)d_in[4];
    const float* tr1  = (const float*)d_in[5];
    const float* tr2  = (const float*)d_in[6];
    const float* cp   = (const float*)d_in[7];

    float* tbl = (float*)d_ws;                       // NBLK*16 floats = 1.18 MB
    float* partial = tbl + (size_t)NBLK * 16;        // Bn*NCH*PLANE floats = 18.9 MB
    const size_t need = ((size_t)NBLK * 16 + (size_t)Bn * NCH * PLANE) * sizeof(float);

    tbl_kernel<<<(NBLK + 255) / 256, 256, 0, stream>>>(rot0, rot1, rot2, tr1, tr2, cp, tbl);

    if (ws_size >= need) {
        warp_tiled<true><<<NBLK, 256, 0, stream>>>(x, tbl, (float*)d_out, partial);
        reduce_kernel<<<(N2D + 255) / 256, 256, 0, stream>>>(partial, yin, (float*)d_out);
    } else {
        warp_tiled<false><<<NBLK, 256, 0, stream>>>(x, tbl, (float*)d_out, partial);
        reduce_fallback_kernel<<<(N2D + 255) / 256, 256, 0, stream>>>(yin, (float*)d_out);
    }
}